// Round 2
// baseline (471.534 us; speedup 1.0000x reference)
//
#include <hip/hip_runtime.h>
#include <math.h>

#define TOKENS 16384
#define HIDDEN 2048
#define NEXP   64
#define MT     64          // tokens per block (phase1 and phase2)
#define KC     64          // K chunk staged in LDS
#define XPAD   68          // LDS row stride in floats: 68*4B = 272 B = 17 x 16B (odd) -> b128 conflict-free

#define GATES_OFF (TOKENS * 2)
#define SEL_OFF   (GATES_OFF + TOKENS * NEXP)
#define Z_OFF     (SEL_OFF + TOKENS * 2)

__device__ __forceinline__ float wave_sum64(float v) {
    #pragma unroll
    for (int s = 1; s < 64; s <<= 1) v += __shfl_xor(v, s, 64);
    return v;
}

// ---------------------------------------------------------------------------
// Phase 1: logits GEMM. Block = 256 threads = 4 waves, all 4 waves cover the
// SAME 64 tokens (lane = token), wave wv covers experts [16*wv, 16*wv+16).
// w[e][k] is wave-uniform -> scalar (SGPR) operand; x staged in LDS, read as
// ds_read_b128 (k-contiguous, no transpose). Split-K over blockIdx.y.
// ---------------------------------------------------------------------------
__global__ __launch_bounds__(256, 2) void gemm_phase(
    const float* __restrict__ x, const float* __restrict__ w,
    float* __restrict__ part0, float* __restrict__ part1, int nks)
{
    __shared__ __align__(16) float xs[MT * XPAD];   // 64*68*4 = 17.4 KB

    const int tid  = threadIdx.x;
    const int t0   = blockIdx.x * MT;
    const int ks   = blockIdx.y;
    const int klen = HIDDEN / nks;                  // 2048 or 1024
    const int kbeg = ks * klen;
    const int wv   = __builtin_amdgcn_readfirstlane(tid >> 6);  // wave id, provably uniform
    const int lane = tid & 63;                      // token within block
    const int e0   = wv * 16;                       // this wave's expert base

    float acc[16];
    #pragma unroll
    for (int i = 0; i < 16; ++i) acc[i] = 0.f;

    const float* xbase = x + (size_t)t0 * HIDDEN + kbeg;
    const float* wbase = w + (size_t)e0 * HIDDEN + kbeg;   // wave-uniform

    // register double-buffer for the x staging loads
    float4 cur[4], nxt[4];
    #pragma unroll
    for (int p = 0; p < 4; ++p) {
        const int f = tid + 256 * p;
        const int t = f >> 4, kq = f & 15;
        cur[p] = *reinterpret_cast<const float4*>(xbase + (size_t)t * HIDDEN + 4 * kq);
    }

    for (int k0 = 0; ; ) {
        __syncthreads();                      // previous chunk's readers done
        #pragma unroll
        for (int p = 0; p < 4; ++p) {
            const int f = tid + 256 * p;
            const int t = f >> 4, kq = f & 15;
            *reinterpret_cast<float4*>(&xs[t * XPAD + 4 * kq]) = cur[p];
        }
        const bool more = (k0 + KC < klen);
        if (more) {
            #pragma unroll
            for (int p = 0; p < 4; ++p) {
                const int f = tid + 256 * p;
                const int t = f >> 4, kq = f & 15;
                nxt[p] = *reinterpret_cast<const float4*>(xbase + (size_t)t * HIDDEN + (k0 + KC) + 4 * kq);
            }
        }
        __syncthreads();                      // LDS tile visible

        #pragma unroll
        for (int kk = 0; kk < KC; kk += 4) {
            const float4 xv = *reinterpret_cast<const float4*>(&xs[lane * XPAD + kk]);
            #pragma unroll
            for (int e = 0; e < 16; ++e) {
                // wave-uniform address -> s_load_dwordx4, SGPR operand in the FMAs
                const float4 wv4 = *reinterpret_cast<const float4*>(wbase + (size_t)e * HIDDEN + k0 + kk);
                acc[e] = fmaf(xv.x, wv4.x, acc[e]);
                acc[e] = fmaf(xv.y, wv4.y, acc[e]);
                acc[e] = fmaf(xv.z, wv4.z, acc[e]);
                acc[e] = fmaf(xv.w, wv4.w, acc[e]);
            }
        }
        if (!more) break;
        k0 += KC;
        #pragma unroll
        for (int p = 0; p < 4; ++p) cur[p] = nxt[p];
    }

    // epilogue: bounce logits through LDS so the global store is coalesced
    __syncthreads();
    #pragma unroll
    for (int j = 0; j < 4; ++j) {
        float4 v = make_float4(acc[4 * j], acc[4 * j + 1], acc[4 * j + 2], acc[4 * j + 3]);
        *reinterpret_cast<float4*>(&xs[lane * XPAD + e0 + 4 * j]) = v;
    }
    __syncthreads();
    float* dst = (ks == 0) ? part0 : part1;
    #pragma unroll
    for (int p = 0; p < 4; ++p) {
        const int f = tid + 256 * p;
        const int t = f >> 4, eq = f & 15;
        const float4 v = *reinterpret_cast<const float4*>(&xs[t * XPAD + 4 * eq]);
        *reinterpret_cast<float4*>(&dst[(size_t)(t0 + t) * NEXP + 4 * eq]) = v;
    }
}

// ---------------------------------------------------------------------------
// Phase 2: routing. Block = 256 threads = 4 waves; block handles 64 tokens,
// each wave 16 tokens; lane = expert. Reads logits (partials summed in fixed
// order -> deterministic), writes multiplier/gates/selected/z-partials.
// ---------------------------------------------------------------------------
__global__ __launch_bounds__(256) void routing(
    const float* __restrict__ p0, const float* __restrict__ p1, int nks,
    float* __restrict__ out, float* __restrict__ zpartial)
{
    __shared__ float zred[4];
    const int tid  = threadIdx.x;
    const int t0   = blockIdx.x * MT;
    const int wave = tid >> 6;
    const int lane = tid & 63;   // = expert index
    float zsum = 0.f;

    for (int tt = 0; tt < 16; ++tt) {
        const int t = wave * 16 + tt;
        const size_t li = (size_t)(t0 + t) * NEXP + lane;
        float v = p0[li];
        if (nks == 2) v += p1[li];

        // argmax with first-index tiebreak (matches jnp.argmax)
        float bv = v; int bi = lane;
        #pragma unroll
        for (int s = 1; s < 64; s <<= 1) {
            const float ov = __shfl_xor(bv, s, 64);
            const int   oi = __shfl_xor(bi, s, 64);
            if (ov > bv || (ov == bv && oi < bi)) { bv = ov; bi = oi; }
        }
        const float max1 = bv; const int s1 = bi;

        // original softmax + logsumexp
        const float e1 = expf(v - max1);
        const float sume = wave_sum64(e1);
        out[GATES_OFF + li] = e1 / sume;
        const float lse = max1 + logf(sume);
        zsum += lse * lse;   // wave-uniform

        // top-1 pass: mask where (max1 - v) / max(|v|, max1) > 2*eps
        const bool mask1 = (max1 - v) > 0.02f * fmaxf(fabsf(v), max1);
        const float sum1 = wave_sum64(mask1 ? 0.f : e1);

        // top-2 pass: exclude s1, argmax again
        float bv2 = (lane == s1) ? -INFINITY : v; int bi2 = lane;
        #pragma unroll
        for (int s = 1; s < 64; s <<= 1) {
            const float ov = __shfl_xor(bv2, s, 64);
            const int   oi = __shfl_xor(bi2, s, 64);
            if (ov > bv2 || (ov == bv2 && oi < bi2)) { bv2 = ov; bi2 = oi; }
        }
        const float max2 = bv2; const int s2 = bi2;

        const bool mask2 = (max2 - v) > 0.02f * fmaxf(fabsf(v), max2);  // factor uses ORIGINAL logits
        const float p2v = (mask2 || lane == s1) ? 0.f : expf(v - max2);
        const float sum2 = wave_sum64(p2v);

        if (lane == 0) {
            const size_t trow = (size_t)(t0 + t) * 2;
            out[trow + 0] = 1.f / sum1;
            out[trow + 1] = 1.f / sum2;
            out[SEL_OFF + trow + 0] = (float)s1;
            out[SEL_OFF + trow + 1] = (float)s2;
        }
    }

    if (lane == 0) zred[wave] = zsum;
    __syncthreads();
    if (tid == 0)
        zpartial[blockIdx.x] = zred[0] + zred[1] + zred[2] + zred[3];
}

__global__ __launch_bounds__(256) void zfinal(
    const float* __restrict__ zpartial, float* __restrict__ out)
{
    const int tid = threadIdx.x;       // 256 threads, 256 partials
    float v = zpartial[tid];
    v = wave_sum64(v);
    __shared__ float red[4];
    if ((tid & 63) == 0) red[tid >> 6] = v;
    __syncthreads();
    if (tid == 0) {
        const float tot = red[0] + red[1] + red[2] + red[3];
        out[Z_OFF] = 0.001f * (tot / (float)TOKENS);
    }
}

extern "C" void kernel_launch(void* const* d_in, const int* in_sizes, int n_in,
                              void* d_out, int out_size, void* d_ws, size_t ws_size,
                              hipStream_t stream) {
    const float* x = (const float*)d_in[0];   // [16384, 2048] fp32
    const float* w = (const float*)d_in[1];   // [64, 2048] fp32
    float* out = (float*)d_out;               // mult(32768) | gates(1048576) | sel(32768) | z(1)

    // partial-0 lives in the gates region of d_out (overwritten by routing);
    // partial-1 needs TOKENS*NEXP floats of ws. Fall back to nks=1 if ws is tiny.
    const size_t need = (size_t)(TOKENS * NEXP + 256) * sizeof(float);
    const int nks = (ws_size >= need) ? 2 : 1;
    float* part0 = out + GATES_OFF;
    float* part1 = (float*)d_ws;
    float* zpartial = (nks == 2) ? ((float*)d_ws + TOKENS * NEXP) : (float*)d_ws;

    dim3 grid(TOKENS / MT, nks);
    gemm_phase<<<grid, 256, 0, stream>>>(x, w, part0, part1, nks);
    routing<<<TOKENS / MT, 256, 0, stream>>>(part0, part1, nks, out, zpartial);
    zfinal<<<1, 256, 0, stream>>>(zpartial, out);
}

// Round 3
// 317.433 us; speedup vs baseline: 1.4855x; 1.4855x over previous
//
#include <hip/hip_runtime.h>
#include <math.h>

#define TOKENS 16384
#define HIDDEN 2048
#define NEXP   64
#define MT     32                  // tokens per block
#define KC     64                  // K chunk
#define NCHUNK (HIDDEN / KC)       // 32
#define NBLK   (TOKENS / MT)       // 512

#define GATES_OFF (TOKENS * 2)
#define SEL_OFF   (GATES_OFF + TOKENS * NEXP)
#define Z_OFF     (SEL_OFF + TOKENS * 2)

#define WIMG_BYTES (NEXP * HIDDEN * 2 * 2)   // 512 KB: fp16 wh+wl fragment image

typedef __attribute__((ext_vector_type(8))) _Float16 f16x8;
typedef __attribute__((ext_vector_type(4))) float    f32x4;

__device__ __forceinline__ float wave_sum64(float v) {
    #pragma unroll
    for (int s = 1; s < 64; s <<= 1) v += __shfl_xor(v, s, 64);
    return v;
}

// ---------------------------------------------------------------------------
// Setup: convert w [64,2048] fp32 -> fp16 (hi, lo*4096) fragment image in ws.
// Image: [chunk 32][r 1024] of 16-B slots; r = eh*512 + term*256 + kh*128 +
// nt*64 + lane. Slot lane l: n = l&15, klocal = (l>>4)*8 + j (verified
// 16x16x32 B-operand layout).
// ---------------------------------------------------------------------------
__global__ __launch_bounds__(256) void wconvert(
    const float* __restrict__ w, uint4* __restrict__ wimg)
{
    const int s = blockIdx.x * 256 + threadIdx.x;     // 0..32767
    const int c    = s >> 10;
    const int r    = s & 1023;
    const int l    = r & 63;
    const int nt   = (r >> 6) & 1;
    const int kh   = (r >> 7) & 1;
    const int term = (r >> 8) & 1;
    const int eh   = (r >> 9) & 1;
    const int e = eh * 32 + nt * 16 + (l & 15);
    const int k = c * KC + kh * 32 + (l >> 4) * 8;

    const float* src = w + (size_t)e * HIDDEN + k;
    union { _Float16 f[8]; uint4 u; } o;
    #pragma unroll
    for (int j = 0; j < 8; ++j) {
        const float v = src[j];
        const _Float16 h = (_Float16)v;
        o.f[j] = (term == 0) ? h : (_Float16)((v - (float)h) * 4096.f);
    }
    wimg[s] = o.u;
}

// ---------------------------------------------------------------------------
// Main: 512 blocks x 256 thr (4 waves: eh = wv&1 expert-half, kh = wv>>1
// k-half). MFMA f16 16x16x32, 2-term split, fused routing epilogue.
// LDS: A 8KB [term2][ks2][mt2][1KB] + B 16KB [eh2][term2][kh2][nt2][1KB],
// reused as logits [kh2][32][66] f32 in the epilogue.
// ---------------------------------------------------------------------------
__global__ __launch_bounds__(256, 2) void router_main(
    const float* __restrict__ x, const uint4* __restrict__ wimg,
    float* __restrict__ out, float* __restrict__ zpartial)
{
    __shared__ __align__(16) unsigned char lds[24576];
    __shared__ float zred[4];
    unsigned char* ldsA = lds;           // 8 KB
    unsigned char* ldsB = lds + 8192;    // 16 KB
    float* lg = (float*)lds;             // epilogue logits [2][32][66]

    const int tid  = threadIdx.x;
    const int wv   = tid >> 6;
    const int lane = tid & 63;
    const int eh   = wv & 1;
    const int kh   = wv >> 1;
    const int t0   = blockIdx.x * MT;

    // ---- x loader mapping: 2 float4/thread; f = tid + 256p ----
    int xt[2], xq[2], aoff[2];
    #pragma unroll
    for (int p = 0; p < 2; ++p) {
        const int f = tid + 256 * p;
        const int qlo = f & 3, t = (f >> 2) & 31, qhi = f >> 7;
        const int q = qlo + 4 * qhi;                 // k float4 index 0..15
        xt[p] = t; xq[p] = q;
        const int m = t & 15, mt = t >> 4;
        const int ks2 = q >> 3;                      // 32-k step
        const int lgp = (q >> 1) & 3;                // lane group (k>>3 within step)
        const int j0  = 4 * (q & 1);
        const int l2  = lgp * 16 + m;                // frag lane
        aoff[p] = (ks2 * 2 + mt) * 1024 + l2 * 16 + j0 * 2;   // term stride +4096
    }
    const float* xrow0 = x + (size_t)(t0 + xt[0]) * HIDDEN + 4 * xq[0];
    const float* xrow1 = x + (size_t)(t0 + xt[1]) * HIDDEN + 4 * xq[1];

    // frag read byte offsets (lane-linear)
    const int aro = kh * 2048 + lane * 16;                       // + term*4096 + mt*1024
    const int bro = eh * 8192 + kh * 2048 + lane * 16;           // + term*4096 + nt*1024

    f32x4 acc0[2][2], acc1[2][2];
    #pragma unroll
    for (int mt = 0; mt < 2; ++mt)
        #pragma unroll
        for (int nt = 0; nt < 2; ++nt) { acc0[mt][nt] = (f32x4)0.f; acc1[mt][nt] = (f32x4)0.f; }

    // prologue: chunk 0 in regs
    float4 curx0 = *(const float4*)(xrow0);
    float4 curx1 = *(const float4*)(xrow1);
    uint4 curb[4];
    #pragma unroll
    for (int pp = 0; pp < 4; ++pp) curb[pp] = wimg[tid + 256 * pp];

    for (int c = 0; c < NCHUNK; ++c) {
        __syncthreads();                      // previous chunk's frag reads done
        // prefetch chunk c+1 (clamped; redundant last iter, harmless)
        const int cn = (c + 1 < NCHUNK) ? c + 1 : NCHUNK - 1;
        float4 nx0 = *(const float4*)(xrow0 + cn * KC);
        float4 nx1 = *(const float4*)(xrow1 + cn * KC);
        uint4 nb[4];
        #pragma unroll
        for (int pp = 0; pp < 4; ++pp) nb[pp] = wimg[cn * 1024 + tid + 256 * pp];

        // convert + stage x (A operand, 2 terms)
        #pragma unroll
        for (int p = 0; p < 2; ++p) {
            const float4 v = p ? curx1 : curx0;
            union { _Float16 f[4]; uint2 u; } hh, ll;
            #pragma unroll
            for (int j = 0; j < 4; ++j) {
                const float s = (&v.x)[j];
                const _Float16 h = (_Float16)s;
                hh.f[j] = h;
                ll.f[j] = (_Float16)((s - (float)h) * 4096.f);
            }
            *(uint2*)(ldsA + aoff[p])        = hh.u;
            *(uint2*)(ldsA + aoff[p] + 4096) = ll.u;
        }
        // stage w image (already fragment-order)
        #pragma unroll
        for (int pp = 0; pp < 4; ++pp)
            *(uint4*)(ldsB + (tid + 256 * pp) * 16) = curb[pp];
        __syncthreads();

        // MFMA: wave (eh, kh) does 32tok x 32exp x 32k of this chunk
        f16x8 Ah[2], Al[2], Bh[2], Bl[2];
        #pragma unroll
        for (int mt = 0; mt < 2; ++mt) {
            Ah[mt] = *(const f16x8*)(ldsA + aro + mt * 1024);
            Al[mt] = *(const f16x8*)(ldsA + aro + mt * 1024 + 4096);
        }
        #pragma unroll
        for (int nt = 0; nt < 2; ++nt) {
            Bh[nt] = *(const f16x8*)(ldsB + bro + nt * 1024);
            Bl[nt] = *(const f16x8*)(ldsB + bro + nt * 1024 + 4096);
        }
        #pragma unroll
        for (int mt = 0; mt < 2; ++mt)
            #pragma unroll
            for (int nt = 0; nt < 2; ++nt) {
                acc0[mt][nt] = __builtin_amdgcn_mfma_f32_16x16x32_f16(Ah[mt], Bh[nt], acc0[mt][nt], 0, 0, 0);
                acc1[mt][nt] = __builtin_amdgcn_mfma_f32_16x16x32_f16(Ah[mt], Bl[nt], acc1[mt][nt], 0, 0, 0);
                acc1[mt][nt] = __builtin_amdgcn_mfma_f32_16x16x32_f16(Al[mt], Bh[nt], acc1[mt][nt], 0, 0, 0);
            }

        curx0 = nx0; curx1 = nx1;
        #pragma unroll
        for (int pp = 0; pp < 4; ++pp) curb[pp] = nb[pp];
    }

    // ---- epilogue: combine terms + kh halves into LDS logits ----
    __syncthreads();
    #pragma unroll
    for (int mt = 0; mt < 2; ++mt)
        #pragma unroll
        for (int nt = 0; nt < 2; ++nt)
            #pragma unroll
            for (int r = 0; r < 4; ++r) {
                const int tok = mt * 16 + (lane >> 4) * 4 + r;       // C/D row
                const int e   = eh * 32 + nt * 16 + (lane & 15);     // C/D col
                lg[(kh * 32 + tok) * 66 + e] = acc0[mt][nt][r] + acc1[mt][nt][r] * (1.f / 4096.f);
            }
    __syncthreads();

    // ---- routing (R1-verified math): wave handles 8 tokens, lane = expert ----
    float zsum = 0.f;
    for (int tt = 0; tt < 8; ++tt) {
        const int t = wv * 8 + tt;
        const float v = lg[t * 66 + lane] + lg[(32 + t) * 66 + lane];

        float bv = v; int bi = lane;
        #pragma unroll
        for (int s = 1; s < 64; s <<= 1) {
            const float ov = __shfl_xor(bv, s, 64);
            const int   oi = __shfl_xor(bi, s, 64);
            if (ov > bv || (ov == bv && oi < bi)) { bv = ov; bi = oi; }
        }
        const float max1 = bv; const int s1 = bi;

        const float e1 = expf(v - max1);
        const float sume = wave_sum64(e1);
        out[GATES_OFF + (size_t)(t0 + t) * NEXP + lane] = e1 / sume;
        const float lse = max1 + logf(sume);
        zsum += lse * lse;

        const bool mask1 = (max1 - v) > 0.02f * fmaxf(fabsf(v), max1);
        const float sum1 = wave_sum64(mask1 ? 0.f : e1);

        float bv2 = (lane == s1) ? -INFINITY : v; int bi2 = lane;
        #pragma unroll
        for (int s = 1; s < 64; s <<= 1) {
            const float ov = __shfl_xor(bv2, s, 64);
            const int   oi = __shfl_xor(bi2, s, 64);
            if (ov > bv2 || (ov == bv2 && oi < bi2)) { bv2 = ov; bi2 = oi; }
        }
        const float max2 = bv2; const int s2 = bi2;

        const bool mask2 = (max2 - v) > 0.02f * fmaxf(fabsf(v), max2);
        const float p2v = (mask2 || lane == s1) ? 0.f : expf(v - max2);
        const float sum2 = wave_sum64(p2v);

        if (lane == 0) {
            const size_t trow = (size_t)(t0 + t) * 2;
            out[trow + 0] = 1.f / sum1;
            out[trow + 1] = 1.f / sum2;
            out[SEL_OFF + trow + 0] = (float)s1;
            out[SEL_OFF + trow + 1] = (float)s2;
        }
    }

    if (lane == 0) zred[wv] = zsum;
    __syncthreads();
    if (tid == 0)
        zpartial[blockIdx.x] = zred[0] + zred[1] + zred[2] + zred[3];
}

__global__ __launch_bounds__(256) void zfinal(
    const float* __restrict__ zpartial, float* __restrict__ out)
{
    const int tid = threadIdx.x;                 // 512 partials, 256 threads
    float v = zpartial[tid] + zpartial[tid + 256];
    v = wave_sum64(v);
    __shared__ float red[4];
    if ((tid & 63) == 0) red[tid >> 6] = v;
    __syncthreads();
    if (tid == 0) {
        const float tot = red[0] + red[1] + red[2] + red[3];
        out[Z_OFF] = 0.001f * (tot / (float)TOKENS);
    }
}

extern "C" void kernel_launch(void* const* d_in, const int* in_sizes, int n_in,
                              void* d_out, int out_size, void* d_ws, size_t ws_size,
                              hipStream_t stream) {
    const float* x = (const float*)d_in[0];   // [16384, 2048] fp32
    const float* w = (const float*)d_in[1];   // [64, 2048] fp32
    float* out = (float*)d_out;               // mult(32768) | gates(1048576) | sel(32768) | z(1)

    uint4* wimg     = (uint4*)d_ws;                               // 512 KB
    float* zpartial = (float*)((char*)d_ws + WIMG_BYTES);         // 512 floats

    wconvert<<<128, 256, 0, stream>>>(w, wimg);
    router_main<<<NBLK, 256, 0, stream>>>(x, wimg, out, zpartial);
    zfinal<<<1, 256, 0, stream>>>(zpartial, out);
}

// Round 4
// 228.575 us; speedup vs baseline: 2.0629x; 1.3887x over previous
//
#include <hip/hip_runtime.h>
#include <math.h>

#define TOKENS 16384
#define HIDDEN 2048
#define NEXP   64
#define MT     32                  // tokens per block
#define KC     64                  // K chunk
#define NCHUNK (HIDDEN / KC)       // 32
#define NBLK   (TOKENS / MT)       // 512

#define GATES_OFF (TOKENS * 2)
#define SEL_OFF   (GATES_OFF + TOKENS * NEXP)
#define Z_OFF     (SEL_OFF + TOKENS * 2)

#define WIMG_BYTES (NEXP * HIDDEN * 2 * 2)   // 512 KB: fp16 wh+wl fragment image

typedef __attribute__((ext_vector_type(8))) _Float16 f16x8;
typedef __attribute__((ext_vector_type(4))) float    f32x4;

__device__ __forceinline__ float wave_sum64(float v) {
    #pragma unroll
    for (int s = 1; s < 64; s <<= 1) v += __shfl_xor(v, s, 64);
    return v;
}

// async global->LDS DMA, 16 B per lane; lds dst must be wave-uniform base
__device__ __forceinline__ void load_lds16(const void* g, void* l) {
    __builtin_amdgcn_global_load_lds(
        (const __attribute__((address_space(1))) unsigned int*)g,
        (__attribute__((address_space(3))) unsigned int*)l, 16, 0, 0);
}

// ---------------------------------------------------------------------------
// Setup: convert w [64,2048] fp32 -> fp16 (hi, lo*4096) fragment image in ws.
// Image: [chunk 32][r 1024] of 16-B slots; r = eh*512 + term*256 + kh*128 +
// nt*64 + lane. Slot lane l: n = l&15, klocal = (l>>4)*8 + j (verified
// 16x16x32 B-operand layout). [verified R3: passed, absmax 2.4e-4]
// ---------------------------------------------------------------------------
__global__ __launch_bounds__(256) void wconvert(
    const float* __restrict__ w, uint4* __restrict__ wimg)
{
    const int s = blockIdx.x * 256 + threadIdx.x;     // 0..32767
    const int c    = s >> 10;
    const int r    = s & 1023;
    const int l    = r & 63;
    const int nt   = (r >> 6) & 1;
    const int kh   = (r >> 7) & 1;
    const int term = (r >> 8) & 1;
    const int eh   = (r >> 9) & 1;
    const int e = eh * 32 + nt * 16 + (l & 15);
    const int k = c * KC + kh * 32 + (l >> 4) * 8;

    const float* src = w + (size_t)e * HIDDEN + k;
    union { _Float16 f[8]; uint4 u; } o;
    #pragma unroll
    for (int j = 0; j < 8; ++j) {
        const float v = src[j];
        const _Float16 h = (_Float16)v;
        o.f[j] = (term == 0) ? h : (_Float16)((v - (float)h) * 4096.f);
    }
    wimg[s] = o.u;
}

// ---------------------------------------------------------------------------
// Main: 512 blocks x 256 thr (4 waves: eh = wv&1 expert-half, kh = wv>>1
// k-half). MFMA f16 16x16x32, 2-term split, fused routing epilogue.
// LDS: A 8KB [term2][ks2][mt2][1KB] + B 16KB [eh2][term2][kh2][nt2][1KB],
// reused as logits [kh2][32][66] f32 in the epilogue.
// R4: B staged by global_load_lds (no register dbuf -> no spill); x prefetch
// issued after the staging barrier so it flies across the MFMA section.
// ---------------------------------------------------------------------------
__global__ __launch_bounds__(256, 3) void router_main(
    const float* __restrict__ x, const uint4* __restrict__ wimg,
    float* __restrict__ out, float* __restrict__ zpartial)
{
    __shared__ __align__(16) unsigned char lds[24576];
    __shared__ float zred[4];
    unsigned char* ldsA = lds;           // 8 KB
    unsigned char* ldsB = lds + 8192;    // 16 KB
    float* lg = (float*)lds;             // epilogue logits [2][32][66]

    const int tid  = threadIdx.x;
    const int wv   = __builtin_amdgcn_readfirstlane(tid >> 6);
    const int lane = tid & 63;
    const int eh   = wv & 1;
    const int kh   = wv >> 1;
    const int t0   = blockIdx.x * MT;

    // ---- x loader mapping: 2 float4/thread; f = tid + 256p ----
    int xt[2], xq[2], aoff[2];
    #pragma unroll
    for (int p = 0; p < 2; ++p) {
        const int f = tid + 256 * p;
        const int qlo = f & 3, t = (f >> 2) & 31, qhi = f >> 7;
        const int q = qlo + 4 * qhi;                 // k float4 index 0..15
        xt[p] = t; xq[p] = q;
        const int m = t & 15, mt = t >> 4;
        const int ks2 = q >> 3;                      // 32-k step
        const int lgp = (q >> 1) & 3;                // lane group (k>>3 within step)
        const int j0  = 4 * (q & 1);
        const int l2  = lgp * 16 + m;                // frag lane
        aoff[p] = (ks2 * 2 + mt) * 1024 + l2 * 16 + j0 * 2;   // term stride +4096
    }
    const float* xrow0 = x + (size_t)(t0 + xt[0]) * HIDDEN + 4 * xq[0];
    const float* xrow1 = x + (size_t)(t0 + xt[1]) * HIDDEN + 4 * xq[1];

    // w DMA addressing: per-wave, 4 instrs of 64 lanes x 16 B = 16 KB/chunk
    const uint4* wsrc = wimg + wv * 64 + lane;       // + c*1024 + p*256
    unsigned char* wdst = ldsB + wv * 1024;          // + p*4096 (uniform)

    // frag read byte offsets (lane-linear)
    const int aro = kh * 2048 + lane * 16;                       // + term*4096 + mt*1024
    const int bro = eh * 8192 + kh * 2048 + lane * 16;           // + term*4096 + nt*1024

    f32x4 acc0[2][2], acc1[2][2];
    #pragma unroll
    for (int mt = 0; mt < 2; ++mt)
        #pragma unroll
        for (int nt = 0; nt < 2; ++nt) { acc0[mt][nt] = (f32x4)0.f; acc1[mt][nt] = (f32x4)0.f; }

    // prologue: chunk 0 x in regs
    float4 curx0 = *(const float4*)(xrow0);
    float4 curx1 = *(const float4*)(xrow1);

    for (int c = 0; c < NCHUNK; ++c) {
        __syncthreads();                      // previous chunk's frag reads done
        // issue async B staging for chunk c (drained by the next barrier)
        #pragma unroll
        for (int p = 0; p < 4; ++p)
            load_lds16(wsrc + c * 1024 + p * 256, wdst + p * 4096);

        // convert + stage x (A operand, 2 terms)
        #pragma unroll
        for (int p = 0; p < 2; ++p) {
            const float4 v = p ? curx1 : curx0;
            union { _Float16 f[4]; uint2 u; } hh, ll;
            #pragma unroll
            for (int j = 0; j < 4; ++j) {
                const float s = (&v.x)[j];
                const _Float16 h = (_Float16)s;
                hh.f[j] = h;
                ll.f[j] = (_Float16)((s - (float)h) * 4096.f);
            }
            *(uint2*)(ldsA + aoff[p])        = hh.u;
            *(uint2*)(ldsA + aoff[p] + 4096) = ll.u;
        }
        __syncthreads();                      // LDS tile visible (drains DMA)

        // prefetch next chunk's x AFTER the barrier: in flight across MFMA,
        // consumed (and thus waited on) only at next iteration's staging.
        float4 nx0 = curx0, nx1 = curx1;
        if (c + 1 < NCHUNK) {
            nx0 = *(const float4*)(xrow0 + (c + 1) * KC);
            nx1 = *(const float4*)(xrow1 + (c + 1) * KC);
        }

        // MFMA: wave (eh, kh) does 32tok x 32exp x 32k of this chunk
        f16x8 Ah[2], Al[2], Bh[2], Bl[2];
        #pragma unroll
        for (int mt = 0; mt < 2; ++mt) {
            Ah[mt] = *(const f16x8*)(ldsA + aro + mt * 1024);
            Al[mt] = *(const f16x8*)(ldsA + aro + mt * 1024 + 4096);
        }
        #pragma unroll
        for (int nt = 0; nt < 2; ++nt) {
            Bh[nt] = *(const f16x8*)(ldsB + bro + nt * 1024);
            Bl[nt] = *(const f16x8*)(ldsB + bro + nt * 1024 + 4096);
        }
        #pragma unroll
        for (int mt = 0; mt < 2; ++mt)
            #pragma unroll
            for (int nt = 0; nt < 2; ++nt) {
                acc0[mt][nt] = __builtin_amdgcn_mfma_f32_16x16x32_f16(Ah[mt], Bh[nt], acc0[mt][nt], 0, 0, 0);
                acc1[mt][nt] = __builtin_amdgcn_mfma_f32_16x16x32_f16(Ah[mt], Bl[nt], acc1[mt][nt], 0, 0, 0);
                acc1[mt][nt] = __builtin_amdgcn_mfma_f32_16x16x32_f16(Al[mt], Bh[nt], acc1[mt][nt], 0, 0, 0);
            }

        curx0 = nx0; curx1 = nx1;
    }

    // ---- epilogue: combine terms + kh halves into LDS logits ----
    __syncthreads();
    #pragma unroll
    for (int mt = 0; mt < 2; ++mt)
        #pragma unroll
        for (int nt = 0; nt < 2; ++nt)
            #pragma unroll
            for (int r = 0; r < 4; ++r) {
                const int tok = mt * 16 + (lane >> 4) * 4 + r;       // C/D row
                const int e   = eh * 32 + nt * 16 + (lane & 15);     // C/D col
                lg[(kh * 32 + tok) * 66 + e] = acc0[mt][nt][r] + acc1[mt][nt][r] * (1.f / 4096.f);
            }
    __syncthreads();

    // ---- routing (R1-verified math): wave handles 8 tokens, lane = expert ----
    float zsum = 0.f;
    for (int tt = 0; tt < 8; ++tt) {
        const int t = wv * 8 + tt;
        const float v = lg[t * 66 + lane] + lg[(32 + t) * 66 + lane];

        float bv = v; int bi = lane;
        #pragma unroll
        for (int s = 1; s < 64; s <<= 1) {
            const float ov = __shfl_xor(bv, s, 64);
            const int   oi = __shfl_xor(bi, s, 64);
            if (ov > bv || (ov == bv && oi < bi)) { bv = ov; bi = oi; }
        }
        const float max1 = bv; const int s1 = bi;

        const float e1 = expf(v - max1);
        const float sume = wave_sum64(e1);
        out[GATES_OFF + (size_t)(t0 + t) * NEXP + lane] = e1 / sume;
        const float lse = max1 + logf(sume);
        zsum += lse * lse;

        const bool mask1 = (max1 - v) > 0.02f * fmaxf(fabsf(v), max1);
        const float sum1 = wave_sum64(mask1 ? 0.f : e1);

        float bv2 = (lane == s1) ? -INFINITY : v; int bi2 = lane;
        #pragma unroll
        for (int s = 1; s < 64; s <<= 1) {
            const float ov = __shfl_xor(bv2, s, 64);
            const int   oi = __shfl_xor(bi2, s, 64);
            if (ov > bv2 || (ov == bv2 && oi < bi2)) { bv2 = ov; bi2 = oi; }
        }
        const float max2 = bv2; const int s2 = bi2;

        const bool mask2 = (max2 - v) > 0.02f * fmaxf(fabsf(v), max2);
        const float p2v = (mask2 || lane == s1) ? 0.f : expf(v - max2);
        const float sum2 = wave_sum64(p2v);

        if (lane == 0) {
            const size_t trow = (size_t)(t0 + t) * 2;
            out[trow + 0] = 1.f / sum1;
            out[trow + 1] = 1.f / sum2;
            out[SEL_OFF + trow + 0] = (float)s1;
            out[SEL_OFF + trow + 1] = (float)s2;
        }
    }

    if (lane == 0) zred[wv] = zsum;
    __syncthreads();
    if (tid == 0)
        zpartial[blockIdx.x] = zred[0] + zred[1] + zred[2] + zred[3];
}

__global__ __launch_bounds__(256) void zfinal(
    const float* __restrict__ zpartial, float* __restrict__ out)
{
    const int tid = threadIdx.x;                 // 512 partials, 256 threads
    float v = zpartial[tid] + zpartial[tid + 256];
    v = wave_sum64(v);
    __shared__ float red[4];
    if ((tid & 63) == 0) red[tid >> 6] = v;
    __syncthreads();
    if (tid == 0) {
        const float tot = red[0] + red[1] + red[2] + red[3];
        out[Z_OFF] = 0.001f * (tot / (float)TOKENS);
    }
}

extern "C" void kernel_launch(void* const* d_in, const int* in_sizes, int n_in,
                              void* d_out, int out_size, void* d_ws, size_t ws_size,
                              hipStream_t stream) {
    const float* x = (const float*)d_in[0];   // [16384, 2048] fp32
    const float* w = (const float*)d_in[1];   // [64, 2048] fp32
    float* out = (float*)d_out;               // mult(32768) | gates(1048576) | sel(32768) | z(1)

    uint4* wimg     = (uint4*)d_ws;                               // 512 KB
    float* zpartial = (float*)((char*)d_ws + WIMG_BYTES);         // 512 floats

    wconvert<<<128, 256, 0, stream>>>(w, wimg);
    router_main<<<NBLK, 256, 0, stream>>>(x, wimg, out, zpartial);
    zfinal<<<1, 256, 0, stream>>>(zpartial, out);
}

// Round 5
// 219.759 us; speedup vs baseline: 2.1457x; 1.0401x over previous
//
#include <hip/hip_runtime.h>
#include <math.h>

#define TOKENS 16384
#define HIDDEN 2048
#define NEXP   64
#define MT     32                  // tokens per block
#define KC     64                  // K chunk
#define NCHUNK (HIDDEN / KC)       // 32
#define NBLK   (TOKENS / MT)       // 512

#define GATES_OFF (TOKENS * 2)
#define SEL_OFF   (GATES_OFF + TOKENS * NEXP)
#define Z_OFF     (SEL_OFF + TOKENS * 2)

#define WIMG_BYTES (NEXP * HIDDEN * 2 * 2)   // 512 KB: fp16 wh+wl fragment image

typedef __attribute__((ext_vector_type(8))) _Float16 f16x8;
typedef __attribute__((ext_vector_type(4))) float    f32x4;

__device__ __forceinline__ float wave_sum64(float v) {
    #pragma unroll
    for (int s = 1; s < 64; s <<= 1) v += __shfl_xor(v, s, 64);
    return v;
}

// ---------------------------------------------------------------------------
// Setup: convert w [64,2048] fp32 -> fp16 (hi, lo*4096) fragment image in ws.
// Image: [chunk 32][r 1024] of 16-B slots; r = eh*512 + term*256 + kh*128 +
// nt*64 + lane. Slot lane l: n = l&15, klocal = (l>>4)*8 + j (verified
// 16x16x32 B-operand layout). [verified R3/R4: passed, absmax 2.4e-4]
// ---------------------------------------------------------------------------
__global__ __launch_bounds__(256) void wconvert(
    const float* __restrict__ w, uint4* __restrict__ wimg)
{
    const int s = blockIdx.x * 256 + threadIdx.x;     // 0..32767
    const int c    = s >> 10;
    const int r    = s & 1023;
    const int l    = r & 63;
    const int nt   = (r >> 6) & 1;
    const int kh   = (r >> 7) & 1;
    const int term = (r >> 8) & 1;
    const int eh   = (r >> 9) & 1;
    const int e = eh * 32 + nt * 16 + (l & 15);
    const int k = c * KC + kh * 32 + (l >> 4) * 8;

    const float* src = w + (size_t)e * HIDDEN + k;
    union { _Float16 f[8]; uint4 u; } o;
    #pragma unroll
    for (int j = 0; j < 8; ++j) {
        const float v = src[j];
        const _Float16 h = (_Float16)v;
        o.f[j] = (term == 0) ? h : (_Float16)((v - (float)h) * 4096.f);
    }
    wimg[s] = o.u;
}

// ---------------------------------------------------------------------------
// Main: 512 blocks x 256 thr (4 waves: eh = wv&1 expert-half, kh = wv>>1
// k-half). MFMA f16 16x16x32, 2-term split, fused routing epilogue.
// R5 restructure: ONE barrier/chunk. A (x) double-buffered in LDS (2 x 8 KB,
// iter c reads buf[c&1], stages c+1 into buf[(c+1)&1]); B fragments go
// global->VGPR directly (lane-linear wimg), prefetched one chunk ahead; x
// prefetched two chunks ahead. LDS reused as logits [2][32][66] in epilogue.
// ---------------------------------------------------------------------------
__global__ __launch_bounds__(256, 3) void router_main(
    const float* __restrict__ x, const uint4* __restrict__ wimg,
    float* __restrict__ out, float* __restrict__ zpartial)
{
    __shared__ __align__(16) unsigned char lds[16896];  // max(2*8KB staging, 16.9KB logits)
    __shared__ float zred[4];
    unsigned char* ldsA = lds;           // two 8 KB A buffers
    float* lg = (float*)lds;             // epilogue logits [2][32][66]

    const int tid  = threadIdx.x;
    const int wv   = __builtin_amdgcn_readfirstlane(tid >> 6);
    const int lane = tid & 63;
    const int eh   = wv & 1;
    const int kh   = wv >> 1;
    const int t0   = blockIdx.x * MT;

    // ---- x loader mapping: 2 float4/thread; f = tid + 256p ----
    int xt[2], xq[2], aoff[2];
    #pragma unroll
    for (int p = 0; p < 2; ++p) {
        const int f = tid + 256 * p;
        const int qlo = f & 3, t = (f >> 2) & 31, qhi = f >> 7;
        const int q = qlo + 4 * qhi;                 // k float4 index 0..15
        xt[p] = t; xq[p] = q;
        const int m = t & 15, mt = t >> 4;
        const int ks2 = q >> 3;                      // 32-k step
        const int lgp = (q >> 1) & 3;                // lane group (k>>3 within step)
        const int j0  = 4 * (q & 1);
        const int l2  = lgp * 16 + m;                // frag lane
        aoff[p] = (ks2 * 2 + mt) * 1024 + l2 * 16 + j0 * 2;   // +term*4096, +buf*8192
    }
    const float* xrow0 = x + (size_t)(t0 + xt[0]) * HIDDEN + 4 * xq[0];
    const float* xrow1 = x + (size_t)(t0 + xt[1]) * HIDDEN + 4 * xq[1];

    // B fragment source: this wave's (eh,kh) slice, lane-linear -> coalesced
    const uint4* wB = wimg + eh * 512 + kh * 128 + lane;   // + c*1024 + term*256 + nt*64

    // A frag read byte offset (lane-linear)
    const int aro = kh * 2048 + lane * 16;                 // + term*4096 + mt*1024 + buf*8192

    f32x4 acc0[2][2], acc1[2][2];
    #pragma unroll
    for (int mt = 0; mt < 2; ++mt)
        #pragma unroll
        for (int nt = 0; nt < 2; ++nt) { acc0[mt][nt] = (f32x4)0.f; acc1[mt][nt] = (f32x4)0.f; }

    // ---- prologue: stage chunk 0 into buf0; prefetch x(1); load B(0) ----
    {
        const float4 v0 = *(const float4*)(xrow0);
        const float4 v1 = *(const float4*)(xrow1);
        #pragma unroll
        for (int p = 0; p < 2; ++p) {
            const float4 v = p ? v1 : v0;
            union { _Float16 f[4]; uint2 u; } hh, ll;
            #pragma unroll
            for (int j = 0; j < 4; ++j) {
                const float s = (&v.x)[j];
                const _Float16 h = (_Float16)s;
                hh.f[j] = h;
                ll.f[j] = (_Float16)((s - (float)h) * 4096.f);
            }
            *(uint2*)(ldsA + aoff[p])        = hh.u;
            *(uint2*)(ldsA + aoff[p] + 4096) = ll.u;
        }
    }
    float4 xA0 = *(const float4*)(xrow0 + KC);     // x(1)
    float4 xA1 = *(const float4*)(xrow1 + KC);
    f16x8 curB[2][2];
    #pragma unroll
    for (int t = 0; t < 2; ++t)
        #pragma unroll
        for (int n = 0; n < 2; ++n)
            curB[t][n] = *reinterpret_cast<const f16x8*>(wB + t * 256 + n * 64);

    for (int c = 0; c < NCHUNK; ++c) {
        __syncthreads();   // publishes buf[c&1]; drains prefetches issued last iter
        const int cbuf = (c & 1) * 8192;
        const int nbuf = 8192 - cbuf;

        // prefetch x(c+2) and B(c+1) EARLY (drained at next barrier)
        float4 xB0 = xA0, xB1 = xA1;
        if (c + 2 < NCHUNK) {
            xB0 = *(const float4*)(xrow0 + (c + 2) * KC);
            xB1 = *(const float4*)(xrow1 + (c + 2) * KC);
        }
        f16x8 nxtB[2][2];
        #pragma unroll
        for (int t = 0; t < 2; ++t)
            #pragma unroll
            for (int n = 0; n < 2; ++n)
                nxtB[t][n] = (c + 1 < NCHUNK)
                    ? *reinterpret_cast<const f16x8*>(wB + (c + 1) * 1024 + t * 256 + n * 64)
                    : curB[t][n];

        // read A frags for chunk c from buf[c&1]
        f16x8 Ah[2], Al[2];
        #pragma unroll
        for (int mt = 0; mt < 2; ++mt) {
            Ah[mt] = *(const f16x8*)(ldsA + cbuf + aro + mt * 1024);
            Al[mt] = *(const f16x8*)(ldsA + cbuf + aro + mt * 1024 + 4096);
        }

        // stage chunk c+1 (from xA regs, loaded one iter ago) into buf[(c+1)&1]
        if (c + 1 < NCHUNK) {
            #pragma unroll
            for (int p = 0; p < 2; ++p) {
                const float4 v = p ? xA1 : xA0;
                union { _Float16 f[4]; uint2 u; } hh, ll;
                #pragma unroll
                for (int j = 0; j < 4; ++j) {
                    const float s = (&v.x)[j];
                    const _Float16 h = (_Float16)s;
                    hh.f[j] = h;
                    ll.f[j] = (_Float16)((s - (float)h) * 4096.f);
                }
                *(uint2*)(ldsA + nbuf + aoff[p])        = hh.u;
                *(uint2*)(ldsA + nbuf + aoff[p] + 4096) = ll.u;
            }
        }

        // MFMA: wave (eh,kh) does 32tok x 32exp x 32k of chunk c
        #pragma unroll
        for (int mt = 0; mt < 2; ++mt)
            #pragma unroll
            for (int nt = 0; nt < 2; ++nt) {
                acc0[mt][nt] = __builtin_amdgcn_mfma_f32_16x16x32_f16(Ah[mt], curB[0][nt], acc0[mt][nt], 0, 0, 0);
                acc1[mt][nt] = __builtin_amdgcn_mfma_f32_16x16x32_f16(Ah[mt], curB[1][nt], acc1[mt][nt], 0, 0, 0);
                acc1[mt][nt] = __builtin_amdgcn_mfma_f32_16x16x32_f16(Al[mt], curB[0][nt], acc1[mt][nt], 0, 0, 0);
            }

        // rotate prefetch registers
        xA0 = xB0; xA1 = xB1;
        #pragma unroll
        for (int t = 0; t < 2; ++t)
            #pragma unroll
            for (int n = 0; n < 2; ++n)
                curB[t][n] = nxtB[t][n];
    }

    // ---- epilogue: combine terms + kh halves into LDS logits ----
    __syncthreads();
    #pragma unroll
    for (int mt = 0; mt < 2; ++mt)
        #pragma unroll
        for (int nt = 0; nt < 2; ++nt)
            #pragma unroll
            for (int r = 0; r < 4; ++r) {
                const int tok = mt * 16 + (lane >> 4) * 4 + r;       // C/D row
                const int e   = eh * 32 + nt * 16 + (lane & 15);     // C/D col
                lg[(kh * 32 + tok) * 66 + e] = acc0[mt][nt][r] + acc1[mt][nt][r] * (1.f / 4096.f);
            }
    __syncthreads();

    // ---- routing (R1-verified math): wave handles 8 tokens, lane = expert ----
    float zsum = 0.f;
    for (int tt = 0; tt < 8; ++tt) {
        const int t = wv * 8 + tt;
        const float v = lg[t * 66 + lane] + lg[(32 + t) * 66 + lane];

        float bv = v; int bi = lane;
        #pragma unroll
        for (int s = 1; s < 64; s <<= 1) {
            const float ov = __shfl_xor(bv, s, 64);
            const int   oi = __shfl_xor(bi, s, 64);
            if (ov > bv || (ov == bv && oi < bi)) { bv = ov; bi = oi; }
        }
        const float max1 = bv; const int s1 = bi;

        const float e1 = expf(v - max1);
        const float sume = wave_sum64(e1);
        out[GATES_OFF + (size_t)(t0 + t) * NEXP + lane] = e1 / sume;
        const float lse = max1 + logf(sume);
        zsum += lse * lse;

        const bool mask1 = (max1 - v) > 0.02f * fmaxf(fabsf(v), max1);
        const float sum1 = wave_sum64(mask1 ? 0.f : e1);

        float bv2 = (lane == s1) ? -INFINITY : v; int bi2 = lane;
        #pragma unroll
        for (int s = 1; s < 64; s <<= 1) {
            const float ov = __shfl_xor(bv2, s, 64);
            const int   oi = __shfl_xor(bi2, s, 64);
            if (ov > bv2 || (ov == bv2 && oi < bi2)) { bv2 = ov; bi2 = oi; }
        }
        const float max2 = bv2; const int s2 = bi2;

        const bool mask2 = (max2 - v) > 0.02f * fmaxf(fabsf(v), max2);
        const float p2v = (mask2 || lane == s1) ? 0.f : expf(v - max2);
        const float sum2 = wave_sum64(p2v);

        if (lane == 0) {
            const size_t trow = (size_t)(t0 + t) * 2;
            out[trow + 0] = 1.f / sum1;
            out[trow + 1] = 1.f / sum2;
            out[SEL_OFF + trow + 0] = (float)s1;
            out[SEL_OFF + trow + 1] = (float)s2;
        }
    }

    if (lane == 0) zred[wv] = zsum;
    __syncthreads();
    if (tid == 0)
        zpartial[blockIdx.x] = zred[0] + zred[1] + zred[2] + zred[3];
}

__global__ __launch_bounds__(256) void zfinal(
    const float* __restrict__ zpartial, float* __restrict__ out)
{
    const int tid = threadIdx.x;                 // 512 partials, 256 threads
    float v = zpartial[tid] + zpartial[tid + 256];
    v = wave_sum64(v);
    __shared__ float red[4];
    if ((tid & 63) == 0) red[tid >> 6] = v;
    __syncthreads();
    if (tid == 0) {
        const float tot = red[0] + red[1] + red[2] + red[3];
        out[Z_OFF] = 0.001f * (tot / (float)TOKENS);
    }
}

extern "C" void kernel_launch(void* const* d_in, const int* in_sizes, int n_in,
                              void* d_out, int out_size, void* d_ws, size_t ws_size,
                              hipStream_t stream) {
    const float* x = (const float*)d_in[0];   // [16384, 2048] fp32
    const float* w = (const float*)d_in[1];   // [64, 2048] fp32
    float* out = (float*)d_out;               // mult(32768) | gates(1048576) | sel(32768) | z(1)

    uint4* wimg     = (uint4*)d_ws;                               // 512 KB
    float* zpartial = (float*)((char*)d_ws + WIMG_BYTES);         // 512 floats

    wconvert<<<128, 256, 0, stream>>>(w, wimg);
    router_main<<<NBLK, 256, 0, stream>>>(x, wimg, out, zpartial);
    zfinal<<<1, 256, 0, stream>>>(zpartial, out);
}